// Round 3
// baseline (508.105 us; speedup 1.0000x reference)
//
#include <hip/hip_runtime.h>
#include <math.h>

// GraphAttention: q,v [G=2048, N=256, D=128] f32; mask [G, N] i32; W [256] f32; b [1] f32
// out [G, D] f32.  Online-softmax single pass, 4 rows per step.
// BW fix: global_load_lds staging of 32-row q/v tiles, double-buffered (64 KB),
// keeps a full 32 KB tile in flight per block (MLP >> register prefetch could hold).
// Compute reads tiles from LDS; DPP-based reduction (1 DS hop per iter) unchanged.

constexpr int NR    = 256;   // rows per group
constexpr int DIM   = 128;   // d_q = d_v
constexpr int TROWS = 32;    // rows per staged tile
constexpr int NT    = NR / TROWS;   // 8 tiles
constexpr float LALPHA  = 0.2f;
constexpr float NEG_INF = -9.0e15f;

#define GLOBAL_AS __attribute__((address_space(1)))
#define LDS_AS    __attribute__((address_space(3)))

// One wave-wide direct-to-LDS load: 64 lanes x 16 B = 1 KB.
// gsrc is PER-LANE (must include lane*16B); lds dst is WAVE-UNIFORM base
// (HW adds lane*16B). Both must be linear/contiguous — layout below is.
__device__ __forceinline__ void stage1k(const float* gsrc, float* lds_uniform) {
    __builtin_amdgcn_global_load_lds((const GLOBAL_AS unsigned int*)gsrc,
                                     (LDS_AS unsigned int*)lds_uniform, 16, 0, 0);
}

// DPP move: result lane i = src lane per CTRL (within 16-lane row / quad).
template<int CTRL>
__device__ __forceinline__ float dpp_mov(float x) {
    return __int_as_float(
        __builtin_amdgcn_update_dpp(0, __float_as_int(x), CTRL, 0xF, 0xF, true));
}
// ctrl: quad_perm(1,0,3,2)=0xB1 (xor1), quad_perm(2,3,0,1)=0x4E (xor2),
//       row_ror:4=0x124, row_ror:8=0x128, quad bcast lane j = j*0x55.

__global__ __launch_bounds__(256) void graph_attn_kernel(
    const float* __restrict__ q,    // [G, NR, DIM]
    const float* __restrict__ v,    // [G, NR, DIM]
    const int*   __restrict__ mask, // [G, NR]
    const float* __restrict__ W,    // [2*DIM]
    const float* __restrict__ bptr, // [1]
    float*       __restrict__ out)  // [G, DIM]
{
    const int g    = blockIdx.x;
    const int t    = threadIdx.x;
    const int hw   = t >> 5;    // half-wave 0..7; owns rows tile*32 + 4*hw .. +3
    const int lane = t & 31;    // lane in half-wave; owns cols 4*lane..4*lane+3
    const int L    = t & 3;     // row-slot within 4-lane group
    const int wvid = t >> 6;    // wave 0..3 (staging work split)
    const int wl   = t & 63;    // lane within physical wave

    __shared__ float bufQ[2][TROWS][DIM];   // 2 x 16 KB
    __shared__ float bufV[2][TROWS][DIM];   // 2 x 16 KB
    __shared__ float s_mask[NR];
    __shared__ float s_m[8], s_l[8];
    __shared__ float s_o[8][DIM];

    s_mask[t] = (mask[g * NR + t] > 0) ? 1.0f : 0.0f;
    __syncthreads();

    const float4 wq  = *(const float4*)(W + lane * 4);
    const float4 wv4 = *(const float4*)(W + DIM + lane * 4);
    const float bias = bptr[0];

    const float* qg = q + (size_t)g * NR * DIM;
    const float* vg = v + (size_t)g * NR * DIM;

    // This thread's mask values, hoisted to registers (row = k*32 + 4*hw + L)
    float mrow[NT];
#pragma unroll
    for (int k = 0; k < NT; ++k) mrow[k] = s_mask[(k << 5) + (hw << 2) + L];

    const bool odd1 = (t & 1) != 0;
    const bool odd2 = (t & 2) != 0;

    // Stage tile tl (rows [32*tl, 32*tl+32) of q and v) into buffer b.
    // 16 KB per array = 16 chunks of 1 KB; wave wvid issues chunks 4*wvid..+3.
    auto STAGE = [&](int b, int tl) {
        const float* qt = qg + (size_t)tl * TROWS * DIM;
        const float* vt = vg + (size_t)tl * TROWS * DIM;
#pragma unroll
        for (int j = 0; j < 4; ++j) {
            const int fo = (wvid * 4 + j) * 256;          // wave-uniform float offset
            stage1k(qt + fo + wl * 4, &bufQ[b][0][0] + fo);
            stage1k(vt + fo + wl * 4, &bufV[b][0][0] + fo);
        }
    };

    // Online softmax state (per half-wave; o distributed: 4 floats/lane)
    float m = -INFINITY;
    float l = 0.0f;
    float4 o = make_float4(0.f, 0.f, 0.f, 0.f);

    STAGE(0, 0);
    __syncthreads();   // vmcnt(0) drain + barrier: tile 0 resident

#pragma unroll
    for (int tl = 0; tl < NT; ++tl) {
        if (tl + 1 < NT) STAGE((tl + 1) & 1, tl + 1);   // next tile in flight

        const int b = tl & 1;
        const float* bq = &bufQ[b][hw << 2][lane << 2];
        const float* bv = &bufV[b][hw << 2][lane << 2];
        const float4 Q0 = *(const float4*)(bq + 0 * DIM);
        const float4 Q1 = *(const float4*)(bq + 1 * DIM);
        const float4 Q2 = *(const float4*)(bq + 2 * DIM);
        const float4 Q3 = *(const float4*)(bq + 3 * DIM);
        const float4 V0 = *(const float4*)(bv + 0 * DIM);
        const float4 V1 = *(const float4*)(bv + 1 * DIM);
        const float4 V2 = *(const float4*)(bv + 2 * DIM);
        const float4 V3 = *(const float4*)(bv + 3 * DIM);

        // Per-lane partial dots for 4 rows over this lane's 4+4 cols
        float pe0 = Q0.x*wq.x + Q0.y*wq.y + Q0.z*wq.z + Q0.w*wq.w
                  + V0.x*wv4.x + V0.y*wv4.y + V0.z*wv4.z + V0.w*wv4.w;
        float pe1 = Q1.x*wq.x + Q1.y*wq.y + Q1.z*wq.z + Q1.w*wq.w
                  + V1.x*wv4.x + V1.y*wv4.y + V1.z*wv4.z + V1.w*wv4.w;
        float pe2 = Q2.x*wq.x + Q2.y*wq.y + Q2.z*wq.z + Q2.w*wq.w
                  + V2.x*wv4.x + V2.y*wv4.y + V2.z*wv4.z + V2.w*wv4.w;
        float pe3 = Q3.x*wq.x + Q3.y*wq.y + Q3.z*wq.z + Q3.w*wq.w
                  + V3.x*wv4.x + V3.y*wv4.y + V3.z*wv4.z + V3.w*wv4.w;

        // Pairing reduction, all DPP: lane ends holding full 32-lane sum for row L
        float sA = (odd1 ? pe1 : pe0) + dpp_mov<0xB1>(odd1 ? pe0 : pe1);
        float sB = (odd1 ? pe3 : pe2) + dpp_mov<0xB1>(odd1 ? pe2 : pe3);
        float s  = (odd2 ? sB  : sA ) + dpp_mov<0x4E>(odd2 ? sA  : sB );
        s += dpp_mov<0x124>(s);     // +4 coset
        s += dpp_mov<0x128>(s);     // +8 coset -> full 16-lane sum
        s += __shfl_xor(s, 16);     // single DS hop: cross 16-group

        float e = s + bias;
        e = fmaxf(e, LALPHA * e);                 // leaky_relu (exact for all signs)
        e = (mrow[tl] > 0.f) ? e : NEG_INF;       // mask fill

        // Max over the 4 rows via quad DPP (uniform across half-wave)
        float gm = fmaxf(e, dpp_mov<0xB1>(e));
        gm = fmaxf(gm, dpp_mov<0x4E>(gm));

        // Shared online-softmax update: one rescale + 2 exps per 4 rows
        const float m_new = fmaxf(m, gm);
        const float scale = __expf(m - m_new);
        const float p     = __expf(e - m_new);    // all-masked rows: exp(0)=1 (matches ref)

        // Gather the 4 rows' p via quad-broadcast DPP
        const float p0 = dpp_mov<0x00>(p);
        const float p1 = dpp_mov<0x55>(p);
        const float p2 = dpp_mov<0xAA>(p);
        const float p3 = dpp_mov<0xFF>(p);

        l = l * scale + ((p0 + p1) + (p2 + p3));
        o.x = o.x * scale + (p0*V0.x + p1*V1.x + p2*V2.x + p3*V3.x);
        o.y = o.y * scale + (p0*V0.y + p1*V1.y + p2*V2.y + p3*V3.y);
        o.z = o.z * scale + (p0*V0.z + p1*V1.z + p2*V2.z + p3*V3.z);
        o.w = o.w * scale + (p0*V0.w + p1*V1.w + p2*V2.w + p3*V3.w);
        m = m_new;

        // Barrier: (a) staged tile tl+1 resident (vmcnt drain), (b) all waves
        // done reading buf[b] before iter tl+1 overwrites buf[b^1]'s sibling.
        __syncthreads();
    }

    // Publish per-half-wave state
    if (lane == 0) { s_m[hw] = m; s_l[hw] = l; }
    *(float4*)(&s_o[hw][lane * 4]) = o;
    __syncthreads();

    // Merge 8 states; threads 0..127 each own one output dim
    if (t < DIM) {
        float M = s_m[0];
#pragma unroll
        for (int i = 1; i < 8; ++i) M = fmaxf(M, s_m[i]);
        float Ls = 0.f, O = 0.f;
#pragma unroll
        for (int i = 0; i < 8; ++i) {
            const float w = __expf(s_m[i] - M);
            Ls += w * s_l[i];
            O += w * s_o[i][t];
        }
        out[(size_t)g * DIM + t] = O / Ls;
    }
}

extern "C" void kernel_launch(void* const* d_in, const int* in_sizes, int n_in,
                              void* d_out, int out_size, void* d_ws, size_t ws_size,
                              hipStream_t stream) {
    const float* q    = (const float*)d_in[0];
    const float* v    = (const float*)d_in[1];
    const int*   mask = (const int*)d_in[2];
    const float* W    = (const float*)d_in[3];
    const float* b    = (const float*)d_in[4];
    float* out = (float*)d_out;

    const int G = in_sizes[0] / (NR * DIM);   // 2048
    graph_attn_kernel<<<G, 256, 0, stream>>>(q, v, mask, W, b, out);
}